// Round 1
// baseline (86.228 us; speedup 1.0000x reference)
//
#include <hip/hip_runtime.h>
#include <stdint.h>

#define NQ 1000
#define NGT 32
#define BS 4
#define NSP 100
#define MNUM 13
#define NPAIR (NGT * MNUM)   // 416
#define QPB 8                // queries per block in cost kernel

__device__ __forceinline__ unsigned int f2sort(float f) {
    unsigned int u = __float_as_uint(f);
    return (u & 0x80000000u) ? ~u : (u | 0x80000000u);
}

// ---------------- Kernel 1: cost matrix C[b][q][g] ----------------
__global__ __launch_bounds__(256) void cost_kernel(
    const float* __restrict__ logits,   // [BS, NQ, 1]
    const float* __restrict__ pbez,     // [BS, NQ, 8]
    const float* __restrict__ tbez,     // [BS, NGT, 4, 2] = 8 floats
    float* __restrict__ C)              // [BS, NQ, NGT]
{
    const int blk = blockIdx.x;         // b*(NQ/QPB) + qc
    const int b  = blk / (NQ / QPB);
    const int qc = blk % (NQ / QPB);
    const int tid = threadIdx.x;

    __shared__ float tpts[NGT][201];    // padded: (g*201+i)%32 = (g*9+i)%32, conflict-free
    __shared__ float ppts[QPB][201];
    __shared__ float cls[QPB];

    // target sample points for this batch
    for (int idx = tid; idx < NGT * NSP; idx += 256) {
        const int g = idx / NSP, s = idx % NSP;
        const float t   = (float)s * (1.0f / 99.0f);
        const float omt = 1.0f - t;
        const float b0 = omt * omt * omt;
        const float b1 = 3.0f * t * omt * omt;
        const float b2 = 3.0f * t * t * omt;
        const float b3 = t * t * t;
        const float* c8 = tbez + ((size_t)b * NGT + g) * 8;
        tpts[g][2 * s]     = b0 * c8[0] + b1 * c8[2] + b2 * c8[4] + b3 * c8[6];
        tpts[g][2 * s + 1] = b0 * c8[1] + b1 * c8[3] + b2 * c8[5] + b3 * c8[7];
    }
    // pred sample points for this block's 8 queries
    for (int idx = tid; idx < QPB * NSP; idx += 256) {
        const int ql = idx / NSP, s = idx % NSP;
        const int q = qc * QPB + ql;
        const float t   = (float)s * (1.0f / 99.0f);
        const float omt = 1.0f - t;
        const float b0 = omt * omt * omt;
        const float b1 = 3.0f * t * omt * omt;
        const float b2 = 3.0f * t * t * omt;
        const float b3 = t * t * t;
        const float* c8 = pbez + ((size_t)b * NQ + q) * 8;
        ppts[ql][2 * s]     = b0 * c8[0] + b1 * c8[2] + b2 * c8[4] + b3 * c8[6];
        ppts[ql][2 * s + 1] = b0 * c8[1] + b1 * c8[3] + b2 * c8[5] + b3 * c8[7];
    }
    // per-query class cost (nc==1 -> tgt class is always 0)
    if (tid < QPB) {
        const int q = qc * QPB + tid;
        const float lg = logits[(size_t)b * NQ + q];
        float p;
        if (lg >= 0.0f) { p = 1.0f / (1.0f + expf(-lg)); }
        else            { const float e = expf(lg); p = e / (1.0f + e); }
        const float pos = 0.25f * (1.0f - p) * (1.0f - p) * (-logf(p + 1e-8f));
        const float neg = 0.75f * p * p * (-log1pf(-p + 1e-8f));
        cls[tid] = pos - neg;
    }
    __syncthreads();

    const int ql = tid >> 5;            // 0..7
    const int g  = tid & 31;            // 0..31
    double acc = 0.0;
    #pragma unroll 8
    for (int i = 0; i < 2 * NSP; ++i)
        acc += (double)fabsf(ppts[ql][i] - tpts[g][i]);
    const int q = qc * QPB + ql;
    C[((size_t)b * NQ + q) * NGT + g] = 2.0f * cls[ql] + 5.0f * (float)acc;
}

// ---------------- Kernel 2: per-column 13 smallest ----------------
__global__ __launch_bounds__(64) void select_kernel(
    const float* __restrict__ C,        // [BS, NQ, NGT]
    int* __restrict__ sel)              // [BS*NGT, MNUM]
{
    const int blk = blockIdx.x;         // b*NGT + g
    const int b = blk / NGT, g = blk % NGT;
    const int lane = threadIdx.x;

    unsigned long long loc[16];
    #pragma unroll
    for (int j = 0; j < 16; ++j) {
        const int q = j * 64 + lane;
        if (q < NQ) {
            const float c = C[((size_t)b * NQ + q) * NGT + g];
            loc[j] = ((unsigned long long)f2sort(c) << 32) | (unsigned int)q;
        } else {
            loc[j] = ~0ull;
        }
    }
    for (int r = 0; r < MNUM; ++r) {
        unsigned long long m = loc[0];
        #pragma unroll
        for (int j = 1; j < 16; ++j) m = (loc[j] < m) ? loc[j] : m;
        #pragma unroll
        for (int off = 1; off < 64; off <<= 1) {
            const unsigned long long o = __shfl_xor(m, off, 64);
            m = (o < m) ? o : m;
        }
        const int q = (int)(m & 0xFFFFFFFFu);
        if (lane == (q & 63)) loc[q >> 6] = ~0ull;   // remove winner
        if (lane == 0) sel[blk * MNUM + r] = q;
    }
}

// ---------------- Kernel 3: per-batch assembly ----------------
__global__ __launch_bounds__(256) void assemble_kernel(
    const float* __restrict__ C,        // [BS, NQ, NGT]
    const int* __restrict__ sel,        // [BS*NGT, MNUM]
    int* __restrict__ out)              // [BS*NPAIR src | BS*NPAIR tgt | BS counts]
{
    const int b = blockIdx.x;
    const int tid = threadIdx.x;

    __shared__ unsigned long long key[NQ];
    __shared__ int cnts[256];
    __shared__ int offs[257];

    for (int q = tid; q < NQ; q += 256) key[q] = ~0ull;
    __syncthreads();

    // scatter: per selected (q,g) pair, min (cost, g) per query
    for (int j = tid; j < NPAIR; j += 256) {
        const int g = j / MNUM;
        const int q = sel[(b * NGT + g) * MNUM + (j % MNUM)];
        const float c = C[((size_t)b * NQ + q) * NGT + g];
        const unsigned long long k =
            ((unsigned long long)f2sort(c) << 32) | (unsigned int)g;
        atomicMin(&key[q], k);
    }
    __syncthreads();

    // flags + block scan (4 queries per thread; 256*4 = 1024 >= NQ)
    const int base = tid * 4;
    int lc = 0;
    for (int k = 0; k < 4; ++k) {
        const int q = base + k;
        if (q < NQ && key[q] != ~0ull) lc++;
    }
    cnts[tid] = lc;
    __syncthreads();
    if (tid == 0) {
        int run = 0;
        for (int i = 0; i < 256; ++i) { offs[i] = run; run += cnts[i]; }
        offs[256] = run;
    }
    __syncthreads();

    const int total = offs[256];
    int* src_out = out + b * NPAIR;
    int* tgt_out = out + BS * NPAIR + b * NPAIR;

    int pos = offs[tid];
    for (int k = 0; k < 4; ++k) {
        const int q = base + k;
        if (q < NQ && key[q] != ~0ull) {
            src_out[pos] = q;
            tgt_out[pos] = (int)(key[q] & 0xFFFFFFFFu);
            pos++;
        }
    }
    for (int i = total + tid; i < NPAIR; i += 256) {
        src_out[i] = NQ;     // padding sentinel = nq = 1000
        tgt_out[i] = -1;
    }
    if (tid == 0) out[2 * BS * NPAIR + b] = total;
}

extern "C" void kernel_launch(void* const* d_in, const int* in_sizes, int n_in,
                              void* d_out, int out_size, void* d_ws, size_t ws_size,
                              hipStream_t stream) {
    const float* logits = (const float*)d_in[0];   // [4,1000,1]
    const float* pbez   = (const float*)d_in[1];   // [4,1000,8]
    // d_in[2] = tgt_labels: nc==1 so every valid label is 0 -> unused
    const float* tbez   = (const float*)d_in[3];   // [4,32,4,2]

    float* C   = (float*)d_ws;                               // 512 KB
    int*   sel = (int*)((char*)d_ws + (size_t)BS * NQ * NGT * sizeof(float));
    int*   out = (int*)d_out;

    cost_kernel<<<BS * (NQ / QPB), 256, 0, stream>>>(logits, pbez, tbez, C);
    select_kernel<<<BS * NGT, 64, 0, stream>>>(C, sel);
    assemble_kernel<<<BS, 256, 0, stream>>>(C, sel, out);
}